// Round 1
// baseline (7928.836 us; speedup 1.0000x reference)
//
#include <hip/hip_runtime.h>
#include <hip/hip_bf16.h>

// Problem constants
#define BATCH 8
#define SEQ   1024
#define CDIM  768
#define HEADS 12
#define HD    64
#define SCALE 0.125f

#define NBINS (1 << 18)
#define TMIN  (-20.0f)
#define BINW  (20.0f / (float)NBINS)
#define INV_BINW ((float)NBINS / 20.0f)
#define K_NEED 2516582u   // int(12*1024*1024*0.2)

// ---------------------------------------------------------------------------
// Kernel 1: qkv = x @ W_qkv, scattered into q,k,v [B,H,N,hd]
// ---------------------------------------------------------------------------
__global__ __launch_bounds__(256) void qkv_gemm(const float* __restrict__ x,
                                                const float* __restrict__ W,
                                                float* __restrict__ q,
                                                float* __restrict__ k,
                                                float* __restrict__ v) {
    const int K = 768, NN = 2304;
    int tM = blockIdx.x * 64;
    int tN = blockIdx.y * 64;
    __shared__ float As[16][65];
    __shared__ float Bs[16][68];
    int tid = threadIdx.x;
    int tx = tid & 15, ty = tid >> 4;
    float acc[4][4] = {};
    for (int k0 = 0; k0 < K; k0 += 16) {
        {
            int r = tid >> 2, c4 = (tid & 3) * 4;
            float4 a = *reinterpret_cast<const float4*>(&x[(size_t)(tM + r) * K + k0 + c4]);
            As[c4 + 0][r] = a.x; As[c4 + 1][r] = a.y; As[c4 + 2][r] = a.z; As[c4 + 3][r] = a.w;
        }
        {
            int r = tid >> 4, c4 = (tid & 15) * 4;
            float4 bv = *reinterpret_cast<const float4*>(&W[(size_t)(k0 + r) * NN + tN + c4]);
            *reinterpret_cast<float4*>(&Bs[r][c4]) = bv;
        }
        __syncthreads();
#pragma unroll
        for (int kk = 0; kk < 16; ++kk) {
            float a[4], bb[4];
#pragma unroll
            for (int i = 0; i < 4; ++i) a[i] = As[kk][ty * 4 + i];
#pragma unroll
            for (int j = 0; j < 4; ++j) bb[j] = Bs[kk][tx * 4 + j];
#pragma unroll
            for (int i = 0; i < 4; ++i)
#pragma unroll
                for (int j = 0; j < 4; ++j) acc[i][j] += a[i] * bb[j];
        }
        __syncthreads();
    }
#pragma unroll
    for (int i = 0; i < 4; ++i) {
        int row = tM + ty * 4 + i;
        int b = row >> 10, n = row & 1023;
#pragma unroll
        for (int j = 0; j < 4; ++j) {
            int col = tN + tx * 4 + j;
            int three = col / 768;
            int r = col % 768;
            int h = r >> 6, d = r & 63;
            float* dst = (three == 0) ? q : (three == 1) ? k : v;
            dst[(((size_t)(b * HEADS + h) << 10) + n) * HD + d] = acc[i][j];
        }
    }
}

// ---------------------------------------------------------------------------
// Kernel 2: per-row softmax stats (o = m + log l) + global histogram of t=s-o
// One block = (b, h, 4 q-rows); one wave per row.
// ---------------------------------------------------------------------------
__global__ __launch_bounds__(256) void stats_hist(const float* __restrict__ q,
                                                  const float* __restrict__ k,
                                                  float* __restrict__ orow,
                                                  unsigned* __restrict__ hist) {
    __shared__ float kb[128][65];
    __shared__ float qs[4][64];
    __shared__ float srow[4][1024];
    int bid = blockIdx.x;
    int qb = bid & 255;
    int bh = bid >> 8;
    int b = bh / HEADS;
    int tid = threadIdx.x, wave = tid >> 6, lane = tid & 63;
    const float* qbase = q + ((size_t)bh * SEQ + qb * 4) * HD;
    const float* kbase = k + (size_t)bh * SEQ * HD;

    qs[tid >> 6][tid & 63] = qbase[tid];
    __syncthreads();
    float qreg[64];
#pragma unroll
    for (int d = 0; d < 64; ++d) qreg[d] = qs[wave][d];

    for (int c = 0; c < 8; ++c) {
        __syncthreads();
#pragma unroll
        for (int i = 0; i < 8; ++i) {
            int fid = i * 256 + tid;
            int jr = fid >> 4, d4 = (fid & 15) * 4;
            float4 kv = *reinterpret_cast<const float4*>(&kbase[((size_t)(c * 128 + jr) << 6) + d4]);
            kb[jr][d4 + 0] = kv.x; kb[jr][d4 + 1] = kv.y; kb[jr][d4 + 2] = kv.z; kb[jr][d4 + 3] = kv.w;
        }
        __syncthreads();
#pragma unroll
        for (int jj = 0; jj < 2; ++jj) {
            int j = jj * 64 + lane;
            float acc = 0.f;
#pragma unroll
            for (int d = 0; d < 64; ++d) acc += qreg[d] * kb[j][d];
            srow[wave][c * 128 + j] = acc * SCALE;
        }
    }
    // each lane reads back exactly the values it wrote (same-wave order holds)
    float sv[16];
#pragma unroll
    for (int i = 0; i < 16; ++i) sv[i] = srow[wave][i * 64 + lane];
    float m = sv[0];
#pragma unroll
    for (int i = 1; i < 16; ++i) m = fmaxf(m, sv[i]);
#pragma unroll
    for (int off = 32; off >= 1; off >>= 1) m = fmaxf(m, __shfl_xor(m, off, 64));
    float l = 0.f;
#pragma unroll
    for (int i = 0; i < 16; ++i) l += __expf(sv[i] - m);
#pragma unroll
    for (int off = 32; off >= 1; off >>= 1) l += __shfl_xor(l, off, 64);
    float o = m + __logf(l);
    if (lane == 0) orow[(size_t)bh * SEQ + qb * 4 + wave] = o;

    unsigned* hb = hist + (size_t)b * NBINS;
#pragma unroll
    for (int i = 0; i < 16; ++i) {
        float t = sv[i] - o;
        int bin = (int)((t - TMIN) * INV_BINW);
        bin = bin < 0 ? 0 : (bin > NBINS - 1 ? NBINS - 1 : bin);
        atomicAdd(&hb[bin], 1u);
    }
}

// ---------------------------------------------------------------------------
// Kernel 3: per-batch threshold from histogram (k-th largest, lower bin edge)
// ---------------------------------------------------------------------------
__global__ __launch_bounds__(256) void find_thr(const unsigned* __restrict__ hist,
                                                float* __restrict__ thr) {
    __shared__ unsigned cs[256];
    __shared__ unsigned bv[1024];
    __shared__ unsigned ps[256];
    __shared__ int chunk_sh;
    __shared__ unsigned above_sh;
    int b = blockIdx.x, tid = threadIdx.x;
    const unsigned* hb = hist + (size_t)b * NBINS;
    const int CHUNK = NBINS / 256;  // 1024

    unsigned ssum = 0;
    for (int i = 0; i < CHUNK; i += 4) {
        uint4 hv = *reinterpret_cast<const uint4*>(&hb[(size_t)tid * CHUNK + i]);
        ssum += hv.x + hv.y + hv.z + hv.w;
    }
    cs[tid] = ssum;
    __syncthreads();
    unsigned suf = 0;
    for (int j = tid; j < 256; ++j) suf += cs[j];
    unsigned above = suf - cs[tid];
    if (suf >= K_NEED && above < K_NEED) { chunk_sh = tid; above_sh = above; }
    __syncthreads();
    int ci = chunk_sh;
    unsigned above_chunk = above_sh;

#pragma unroll
    for (int i = 0; i < 4; ++i) bv[tid * 4 + i] = hb[(size_t)ci * CHUNK + tid * 4 + i];
    ps[tid] = bv[tid * 4] + bv[tid * 4 + 1] + bv[tid * 4 + 2] + bv[tid * 4 + 3];
    __syncthreads();
    unsigned suf2 = 0;
    for (int j = tid + 1; j < 256; ++j) suf2 += ps[j];
    unsigned acc0 = above_chunk + suf2;
    if (acc0 < K_NEED) {
        unsigned acc = acc0;
        for (int bb = 3; bb >= 0; --bb) {
            acc += bv[tid * 4 + bb];
            if (acc >= K_NEED) {
                int bin = ci * CHUNK + tid * 4 + bb;
                thr[b] = TMIN + (float)bin * BINW;  // lower edge of containing bin
                break;
            }
        }
    }
}

// ---------------------------------------------------------------------------
// Kernel 4: PV with threshold mask; writes pre-proj [B,N,C]
// ---------------------------------------------------------------------------
__global__ __launch_bounds__(256) void pv_kernel(const float* __restrict__ q,
                                                 const float* __restrict__ k,
                                                 const float* __restrict__ v,
                                                 const float* __restrict__ orow,
                                                 const float* __restrict__ thr,
                                                 float* __restrict__ aout) {
    __shared__ float kb[128][65];
    __shared__ float vb[128][65];
    __shared__ float pbuf[4][128];
    __shared__ float qs[4][64];
    int bid = blockIdx.x;
    int qb = bid & 255;
    int bh = bid >> 8;
    int b = bh / HEADS, h = bh % HEADS;
    int tid = threadIdx.x, wave = tid >> 6, lane = tid & 63;
    const float* qbase = q + ((size_t)bh * SEQ + qb * 4) * HD;
    const float* kbase = k + (size_t)bh * SEQ * HD;
    const float* vbase = v + (size_t)bh * SEQ * HD;

    qs[tid >> 6][tid & 63] = qbase[tid];
    __syncthreads();
    float qreg[64];
#pragma unroll
    for (int d = 0; d < 64; ++d) qreg[d] = qs[wave][d];
    float o = orow[(size_t)bh * SEQ + qb * 4 + wave];
    float tt = thr[b];
    float outacc = 0.f;

    for (int c = 0; c < 8; ++c) {
        __syncthreads();
#pragma unroll
        for (int i = 0; i < 8; ++i) {
            int fid = i * 256 + tid;
            int jr = fid >> 4, d4 = (fid & 15) * 4;
            size_t goff = ((size_t)(c * 128 + jr) << 6) + d4;
            float4 kv = *reinterpret_cast<const float4*>(&kbase[goff]);
            kb[jr][d4 + 0] = kv.x; kb[jr][d4 + 1] = kv.y; kb[jr][d4 + 2] = kv.z; kb[jr][d4 + 3] = kv.w;
            float4 vv = *reinterpret_cast<const float4*>(&vbase[goff]);
            vb[jr][d4 + 0] = vv.x; vb[jr][d4 + 1] = vv.y; vb[jr][d4 + 2] = vv.z; vb[jr][d4 + 3] = vv.w;
        }
        __syncthreads();
#pragma unroll
        for (int jj = 0; jj < 2; ++jj) {
            int j = jj * 64 + lane;
            float acc = 0.f;
#pragma unroll
            for (int d = 0; d < 64; ++d) acc += qreg[d] * kb[j][d];
            float t = acc * SCALE - o;
            pbuf[wave][j] = (t >= tt) ? __expf(t) : 0.f;
        }
        // same-wave LDS write->read: compiler orders via lgkmcnt
#pragma unroll
        for (int j4 = 0; j4 < 128; j4 += 4) {
            float4 p4 = *reinterpret_cast<const float4*>(&pbuf[wave][j4]);
            outacc += p4.x * vb[j4 + 0][lane];
            outacc += p4.y * vb[j4 + 1][lane];
            outacc += p4.z * vb[j4 + 2][lane];
            outacc += p4.w * vb[j4 + 3][lane];
        }
    }
    aout[((size_t)b * SEQ + qb * 4 + wave) * CDIM + h * HD + lane] = outacc;
}

// ---------------------------------------------------------------------------
// Kernel 5: out = aout @ W_proj + b_proj + origin
// ---------------------------------------------------------------------------
__global__ __launch_bounds__(256) void proj_gemm(const float* __restrict__ A,
                                                 const float* __restrict__ W,
                                                 const float* __restrict__ bias,
                                                 const float* __restrict__ origin,
                                                 float* __restrict__ out) {
    const int K = 768, NN = 768;
    int tM = blockIdx.x * 64;
    int tN = blockIdx.y * 64;
    __shared__ float As[16][65];
    __shared__ float Bs[16][68];
    int tid = threadIdx.x;
    int tx = tid & 15, ty = tid >> 4;
    float acc[4][4] = {};
    for (int k0 = 0; k0 < K; k0 += 16) {
        {
            int r = tid >> 2, c4 = (tid & 3) * 4;
            float4 a = *reinterpret_cast<const float4*>(&A[(size_t)(tM + r) * K + k0 + c4]);
            As[c4 + 0][r] = a.x; As[c4 + 1][r] = a.y; As[c4 + 2][r] = a.z; As[c4 + 3][r] = a.w;
        }
        {
            int r = tid >> 4, c4 = (tid & 15) * 4;
            float4 bv = *reinterpret_cast<const float4*>(&W[(size_t)(k0 + r) * NN + tN + c4]);
            *reinterpret_cast<float4*>(&Bs[r][c4]) = bv;
        }
        __syncthreads();
#pragma unroll
        for (int kk = 0; kk < 16; ++kk) {
            float a[4], bb[4];
#pragma unroll
            for (int i = 0; i < 4; ++i) a[i] = As[kk][ty * 4 + i];
#pragma unroll
            for (int j = 0; j < 4; ++j) bb[j] = Bs[kk][tx * 4 + j];
#pragma unroll
            for (int i = 0; i < 4; ++i)
#pragma unroll
                for (int j = 0; j < 4; ++j) acc[i][j] += a[i] * bb[j];
        }
        __syncthreads();
    }
#pragma unroll
    for (int i = 0; i < 4; ++i) {
        int row = tM + ty * 4 + i;
#pragma unroll
        for (int j = 0; j < 4; ++j) {
            int col = tN + tx * 4 + j;
            out[(size_t)row * NN + col] = acc[i][j] + bias[col] + origin[(size_t)row * NN + col];
        }
    }
}

// ---------------------------------------------------------------------------
extern "C" void kernel_launch(void* const* d_in, const int* in_sizes, int n_in,
                              void* d_out, int out_size, void* d_ws, size_t ws_size,
                              hipStream_t stream) {
    const float* x      = (const float*)d_in[0];
    const float* origin = (const float*)d_in[1];
    const float* W_qkv  = (const float*)d_in[2];
    const float* W_proj = (const float*)d_in[3];
    const float* b_proj = (const float*)d_in[4];
    float* out = (float*)d_out;
    float* ws = (float*)d_ws;

    const size_t QKV_ELEMS = (size_t)BATCH * HEADS * SEQ * HD;  // 6291456
    size_t off = 0;
    float* q = ws + off;    off += QKV_ELEMS;
    float* k = ws + off;    off += QKV_ELEMS;
    float* v = ws + off;    off += QKV_ELEMS;
    float* orow = ws + off; off += (size_t)BATCH * HEADS * SEQ;  // 98304
    float* thr = ws + off;  off += 8;
    unsigned* hist = (unsigned*)(ws + off); off += (size_t)BATCH * NBINS;
    float* aout = ws + off; off += QKV_ELEMS;

    hipMemsetAsync(hist, 0, (size_t)BATCH * NBINS * sizeof(unsigned), stream);
    qkv_gemm<<<dim3(128, 36), 256, 0, stream>>>(x, W_qkv, q, k, v);
    stats_hist<<<dim3(BATCH * HEADS * (SEQ / 4)), 256, 0, stream>>>(q, k, orow, hist);
    find_thr<<<dim3(BATCH), 256, 0, stream>>>(hist, thr);
    pv_kernel<<<dim3(BATCH * HEADS * (SEQ / 4)), 256, 0, stream>>>(q, k, v, orow, thr, aout);
    proj_gemm<<<dim3(128, 12), 256, 0, stream>>>(aout, W_proj, b_proj, origin, out);
}

// Round 2
// 4581.541 us; speedup vs baseline: 1.7306x; 1.7306x over previous
//
#include <hip/hip_runtime.h>
#include <hip/hip_bf16.h>

// Problem constants
#define BATCH 8
#define SEQ   1024
#define CDIM  768
#define HEADS 12
#define HD    64
#define SCALE 0.125f

// Coarse histogram: 4096 bins over t = s - o in [-16, 0].  t <= 0 always
// (o = m + log l >= m >= s).  Bin width 3.9e-3; threshold-flip error analysis
// says ~3e-4 absmax contribution -> negligible vs 0.11 tolerance.
#define NB1   4096
#define TMIN1 (-16.0f)
#define WC    (16.0f / (float)NB1)
#define INV_WC ((float)NB1 / 16.0f)
#define K_NEED 2516582u   // int(12*1024*1024*0.2)

// ---------------------------------------------------------------------------
// Kernel 1: qkv = x @ W_qkv, scattered into q,k,v [B,H,N,hd]
// ---------------------------------------------------------------------------
__global__ __launch_bounds__(256) void qkv_gemm(const float* __restrict__ x,
                                                const float* __restrict__ W,
                                                float* __restrict__ q,
                                                float* __restrict__ k,
                                                float* __restrict__ v) {
    const int K = 768, NN = 2304;
    int tM = blockIdx.x * 64;
    int tN = blockIdx.y * 64;
    __shared__ float As[16][68];   // stride 68 floats = 272 B (16B-mult) -> b128 reads
    __shared__ float Bs[16][68];
    int tid = threadIdx.x;
    int tx = tid & 15, ty = tid >> 4;
    float acc[4][4] = {};
    for (int k0 = 0; k0 < K; k0 += 16) {
        {
            int r = tid >> 2, c4 = (tid & 3) * 4;
            float4 a = *reinterpret_cast<const float4*>(&x[(size_t)(tM + r) * K + k0 + c4]);
            As[c4 + 0][r] = a.x; As[c4 + 1][r] = a.y; As[c4 + 2][r] = a.z; As[c4 + 3][r] = a.w;
        }
        {
            int r = tid >> 4, c4 = (tid & 15) * 4;
            float4 bv = *reinterpret_cast<const float4*>(&W[(size_t)(k0 + r) * NN + tN + c4]);
            *reinterpret_cast<float4*>(&Bs[r][c4]) = bv;
        }
        __syncthreads();
#pragma unroll
        for (int kk = 0; kk < 16; ++kk) {
            float4 av = *reinterpret_cast<const float4*>(&As[kk][ty * 4]);
            float4 bv = *reinterpret_cast<const float4*>(&Bs[kk][tx * 4]);
            float a[4] = {av.x, av.y, av.z, av.w};
            float bb[4] = {bv.x, bv.y, bv.z, bv.w};
#pragma unroll
            for (int i = 0; i < 4; ++i)
#pragma unroll
                for (int j = 0; j < 4; ++j) acc[i][j] += a[i] * bb[j];
        }
        __syncthreads();
    }
#pragma unroll
    for (int i = 0; i < 4; ++i) {
        int row = tM + ty * 4 + i;
        int b = row >> 10, n = row & 1023;
#pragma unroll
        for (int j = 0; j < 4; ++j) {
            int col = tN + tx * 4 + j;
            int three = col / 768;
            int r = col % 768;
            int h = r >> 6, d = r & 63;
            float* dst = (three == 0) ? q : (three == 1) ? k : v;
            dst[(((size_t)(b * HEADS + h) << 10) + n) * HD + d] = acc[i][j];
        }
    }
}

// ---------------------------------------------------------------------------
// Kernel 2: per-row softmax stats (o = m + log l) + LDS-private coarse hist.
// Block = (bh, 64 q-rows as 16 sub-chunks of 4); one wave per row per sub.
// Global atomics only at the block->global merge (<=4096 per block).
// ---------------------------------------------------------------------------
__global__ __launch_bounds__(256) void stats_coarse(const float* __restrict__ q,
                                                    const float* __restrict__ k,
                                                    float* __restrict__ orow,
                                                    unsigned* __restrict__ hist) {
    __shared__ float kb[128][65];
    __shared__ float qs[4][64];
    __shared__ unsigned hl[NB1];
    int bid = blockIdx.x;
    int grp = bid & 15;
    int bh = bid >> 4;
    int b = bh / HEADS;
    int tid = threadIdx.x, wave = tid >> 6, lane = tid & 63;
    const float* kbase = k + (size_t)bh * SEQ * HD;
    unsigned* hb = hist + (size_t)b * NB1;

    for (int i = tid; i < NB1; i += 256) hl[i] = 0;

    for (int sub = 0; sub < 16; ++sub) {
        int row0 = grp * 64 + sub * 4;
        __syncthreads();   // protects qs reuse (and hl init on first iter)
        qs[tid >> 6][tid & 63] = q[((size_t)bh * SEQ + row0) * HD + tid];
        __syncthreads();
        float qreg[64];
#pragma unroll
        for (int d = 0; d < 64; ++d) qreg[d] = qs[wave][d];

        float sv[16];
        for (int c = 0; c < 8; ++c) {
            __syncthreads();
#pragma unroll
            for (int i = 0; i < 8; ++i) {
                int fid = i * 256 + tid;
                int jr = fid >> 4, d4 = (fid & 15) * 4;
                float4 kv = *reinterpret_cast<const float4*>(&kbase[((size_t)(c * 128 + jr) << 6) + d4]);
                kb[jr][d4 + 0] = kv.x; kb[jr][d4 + 1] = kv.y; kb[jr][d4 + 2] = kv.z; kb[jr][d4 + 3] = kv.w;
            }
            __syncthreads();
#pragma unroll
            for (int jj = 0; jj < 2; ++jj) {
                int j = jj * 64 + lane;
                float acc = 0.f;
#pragma unroll
                for (int d = 0; d < 64; ++d) acc += qreg[d] * kb[j][d];
                sv[c * 2 + jj] = acc * SCALE;
            }
        }
        float m = sv[0];
#pragma unroll
        for (int i = 1; i < 16; ++i) m = fmaxf(m, sv[i]);
#pragma unroll
        for (int off = 32; off >= 1; off >>= 1) m = fmaxf(m, __shfl_xor(m, off, 64));
        float l = 0.f;
#pragma unroll
        for (int i = 0; i < 16; ++i) l += __expf(sv[i] - m);
#pragma unroll
        for (int off = 32; off >= 1; off >>= 1) l += __shfl_xor(l, off, 64);
        float o = m + __logf(l);
        if (lane == 0) orow[(size_t)bh * SEQ + row0 + wave] = o;

#pragma unroll
        for (int i = 0; i < 16; ++i) {
            float t = sv[i] - o;
            int bin = (int)((t - TMIN1) * INV_WC);
            bin = bin < 0 ? 0 : (bin > NB1 - 1 ? NB1 - 1 : bin);
            atomicAdd(&hl[bin], 1u);
        }
    }
    __syncthreads();
    for (int i = tid; i < NB1; i += 256) {
        unsigned c0 = hl[i];
        if (c0) atomicAdd(&hb[i], c0);
    }
}

// ---------------------------------------------------------------------------
// Kernel 3: per-batch threshold = lower edge of coarse bin holding k-th largest
// ---------------------------------------------------------------------------
__global__ __launch_bounds__(256) void find_thr(const unsigned* __restrict__ hist,
                                                float* __restrict__ thr) {
    __shared__ unsigned cs[256];
    int b = blockIdx.x, tid = threadIdx.x;
    const unsigned* hb = hist + (size_t)b * NB1;
    unsigned s = 0;
#pragma unroll
    for (int i = 0; i < 16; ++i) s += hb[tid * 16 + i];
    cs[tid] = s;
    __syncthreads();
    unsigned suf = 0;
    for (int j = tid; j < 256; ++j) suf += cs[j];
    unsigned above = suf - cs[tid];
    if (suf >= K_NEED && above < K_NEED) {
        unsigned acc = above;
        for (int bb = 15; bb >= 0; --bb) {
            acc += hb[tid * 16 + bb];
            if (acc >= K_NEED) {
                thr[b] = TMIN1 + (float)(tid * 16 + bb) * WC;
                break;
            }
        }
    }
}

// ---------------------------------------------------------------------------
// Kernel 4: PV with threshold mask; writes pre-proj [B,N,C]
// ---------------------------------------------------------------------------
__global__ __launch_bounds__(256) void pv_kernel(const float* __restrict__ q,
                                                 const float* __restrict__ k,
                                                 const float* __restrict__ v,
                                                 const float* __restrict__ orow,
                                                 const float* __restrict__ thr,
                                                 float* __restrict__ aout) {
    __shared__ float kb[128][65];
    __shared__ float vb[128][65];
    __shared__ float pbuf[4][128];
    __shared__ float qs[4][64];
    int bid = blockIdx.x;
    int qb = bid & 255;
    int bh = bid >> 8;
    int b = bh / HEADS, h = bh % HEADS;
    int tid = threadIdx.x, wave = tid >> 6, lane = tid & 63;
    const float* qbase = q + ((size_t)bh * SEQ + qb * 4) * HD;
    const float* kbase = k + (size_t)bh * SEQ * HD;
    const float* vbase = v + (size_t)bh * SEQ * HD;

    qs[tid >> 6][tid & 63] = qbase[tid];
    __syncthreads();
    float qreg[64];
#pragma unroll
    for (int d = 0; d < 64; ++d) qreg[d] = qs[wave][d];
    float o = orow[(size_t)bh * SEQ + qb * 4 + wave];
    float tt = thr[b];
    float outacc = 0.f;

    for (int c = 0; c < 8; ++c) {
        __syncthreads();
#pragma unroll
        for (int i = 0; i < 8; ++i) {
            int fid = i * 256 + tid;
            int jr = fid >> 4, d4 = (fid & 15) * 4;
            size_t goff = ((size_t)(c * 128 + jr) << 6) + d4;
            float4 kv = *reinterpret_cast<const float4*>(&kbase[goff]);
            kb[jr][d4 + 0] = kv.x; kb[jr][d4 + 1] = kv.y; kb[jr][d4 + 2] = kv.z; kb[jr][d4 + 3] = kv.w;
            float4 vv = *reinterpret_cast<const float4*>(&vbase[goff]);
            vb[jr][d4 + 0] = vv.x; vb[jr][d4 + 1] = vv.y; vb[jr][d4 + 2] = vv.z; vb[jr][d4 + 3] = vv.w;
        }
        __syncthreads();
#pragma unroll
        for (int jj = 0; jj < 2; ++jj) {
            int j = jj * 64 + lane;
            float acc = 0.f;
#pragma unroll
            for (int d = 0; d < 64; ++d) acc += qreg[d] * kb[j][d];
            float t = acc * SCALE - o;
            pbuf[wave][j] = (t >= tt) ? __expf(t) : 0.f;
        }
        // same-wave LDS write->read: compiler orders via lgkmcnt
#pragma unroll
        for (int j4 = 0; j4 < 128; j4 += 4) {
            float4 p4 = *reinterpret_cast<const float4*>(&pbuf[wave][j4]);
            outacc += p4.x * vb[j4 + 0][lane];
            outacc += p4.y * vb[j4 + 1][lane];
            outacc += p4.z * vb[j4 + 2][lane];
            outacc += p4.w * vb[j4 + 3][lane];
        }
    }
    aout[((size_t)b * SEQ + qb * 4 + wave) * CDIM + h * HD + lane] = outacc;
}

// ---------------------------------------------------------------------------
// Kernel 5: out = aout @ W_proj + b_proj + origin
// ---------------------------------------------------------------------------
__global__ __launch_bounds__(256) void proj_gemm(const float* __restrict__ A,
                                                 const float* __restrict__ W,
                                                 const float* __restrict__ bias,
                                                 const float* __restrict__ origin,
                                                 float* __restrict__ out) {
    const int K = 768, NN = 768;
    int tM = blockIdx.x * 64;
    int tN = blockIdx.y * 64;
    __shared__ float As[16][68];
    __shared__ float Bs[16][68];
    int tid = threadIdx.x;
    int tx = tid & 15, ty = tid >> 4;
    float acc[4][4] = {};
    for (int k0 = 0; k0 < K; k0 += 16) {
        {
            int r = tid >> 2, c4 = (tid & 3) * 4;
            float4 a = *reinterpret_cast<const float4*>(&A[(size_t)(tM + r) * K + k0 + c4]);
            As[c4 + 0][r] = a.x; As[c4 + 1][r] = a.y; As[c4 + 2][r] = a.z; As[c4 + 3][r] = a.w;
        }
        {
            int r = tid >> 4, c4 = (tid & 15) * 4;
            float4 bv = *reinterpret_cast<const float4*>(&W[(size_t)(k0 + r) * NN + tN + c4]);
            *reinterpret_cast<float4*>(&Bs[r][c4]) = bv;
        }
        __syncthreads();
#pragma unroll
        for (int kk = 0; kk < 16; ++kk) {
            float4 av = *reinterpret_cast<const float4*>(&As[kk][ty * 4]);
            float4 bv = *reinterpret_cast<const float4*>(&Bs[kk][tx * 4]);
            float a[4] = {av.x, av.y, av.z, av.w};
            float bb[4] = {bv.x, bv.y, bv.z, bv.w};
#pragma unroll
            for (int i = 0; i < 4; ++i)
#pragma unroll
                for (int j = 0; j < 4; ++j) acc[i][j] += a[i] * bb[j];
        }
        __syncthreads();
    }
#pragma unroll
    for (int i = 0; i < 4; ++i) {
        int row = tM + ty * 4 + i;
#pragma unroll
        for (int j = 0; j < 4; ++j) {
            int col = tN + tx * 4 + j;
            out[(size_t)row * NN + col] = acc[i][j] + bias[col] + origin[(size_t)row * NN + col];
        }
    }
}

// ---------------------------------------------------------------------------
extern "C" void kernel_launch(void* const* d_in, const int* in_sizes, int n_in,
                              void* d_out, int out_size, void* d_ws, size_t ws_size,
                              hipStream_t stream) {
    const float* x      = (const float*)d_in[0];
    const float* origin = (const float*)d_in[1];
    const float* W_qkv  = (const float*)d_in[2];
    const float* W_proj = (const float*)d_in[3];
    const float* b_proj = (const float*)d_in[4];
    float* out = (float*)d_out;
    float* ws = (float*)d_ws;

    const size_t QKV_ELEMS = (size_t)BATCH * HEADS * SEQ * HD;  // 6291456
    size_t off = 0;
    float* q = ws + off;    off += QKV_ELEMS;
    float* k = ws + off;    off += QKV_ELEMS;
    float* v = ws + off;    off += QKV_ELEMS;
    float* orow = ws + off; off += (size_t)BATCH * HEADS * SEQ;  // 98304
    float* thr = ws + off;  off += 8;
    unsigned* hist = (unsigned*)(ws + off); off += (size_t)BATCH * NB1;
    float* aout = ws + off; off += QKV_ELEMS;

    hipMemsetAsync(hist, 0, (size_t)BATCH * NB1 * sizeof(unsigned), stream);
    qkv_gemm<<<dim3(128, 36), 256, 0, stream>>>(x, W_qkv, q, k, v);
    stats_coarse<<<dim3(BATCH * HEADS * 16), 256, 0, stream>>>(q, k, orow, hist);
    find_thr<<<dim3(BATCH), 256, 0, stream>>>(hist, thr);
    pv_kernel<<<dim3(BATCH * HEADS * (SEQ / 4)), 256, 0, stream>>>(q, k, v, orow, thr, aout);
    proj_gemm<<<dim3(128, 12), 256, 0, stream>>>(aout, W_proj, b_proj, origin, out);
}

// Round 3
// 690.873 us; speedup vs baseline: 11.4765x; 6.6315x over previous
//
#include <hip/hip_runtime.h>
#include <hip/hip_bf16.h>

// Problem constants
#define BATCH 8
#define SEQ   1024
#define CDIM  768
#define HEADS 12
#define HD    64

// Coarse histogram: 4096 bins over t = s - o in [-16, 0], width 1/256.
#define NB1    4096
#define TMIN1  (-16.0f)
#define WC     (1.0f / 256.0f)
#define K_NEED 2516582u   // int(12*1024*1024*0.2)

typedef __attribute__((ext_vector_type(8))) short bf16x8;   // 8 bf16 = 4 VGPR
typedef __attribute__((ext_vector_type(4))) float f32x4;

#define MFMA16(a, b, c) __builtin_amdgcn_mfma_f32_16x16x32_bf16(a, b, c, 0, 0, 0)

// ---------------------------------------------------------------------------
// Kernel 1: qkv = x @ W_qkv (fp32 math), writes bf16 q (pre-scaled), k, v.
// ---------------------------------------------------------------------------
__global__ __launch_bounds__(256) void qkv_gemm(const float* __restrict__ x,
                                                const float* __restrict__ W,
                                                __hip_bfloat16* __restrict__ q,
                                                __hip_bfloat16* __restrict__ k,
                                                __hip_bfloat16* __restrict__ v) {
    const int K = 768, NN = 2304;
    int tM = blockIdx.x * 64;
    int tN = blockIdx.y * 64;
    __shared__ float As[16][68];
    __shared__ float Bs[16][68];
    int tid = threadIdx.x;
    int tx = tid & 15, ty = tid >> 4;
    float acc[4][4] = {};
    for (int k0 = 0; k0 < K; k0 += 16) {
        {
            int r = tid >> 2, c4 = (tid & 3) * 4;
            float4 a = *reinterpret_cast<const float4*>(&x[(size_t)(tM + r) * K + k0 + c4]);
            As[c4 + 0][r] = a.x; As[c4 + 1][r] = a.y; As[c4 + 2][r] = a.z; As[c4 + 3][r] = a.w;
        }
        {
            int r = tid >> 4, c4 = (tid & 15) * 4;
            float4 bv = *reinterpret_cast<const float4*>(&W[(size_t)(k0 + r) * NN + tN + c4]);
            *reinterpret_cast<float4*>(&Bs[r][c4]) = bv;
        }
        __syncthreads();
#pragma unroll
        for (int kk = 0; kk < 16; ++kk) {
            float4 av = *reinterpret_cast<const float4*>(&As[kk][ty * 4]);
            float4 bv = *reinterpret_cast<const float4*>(&Bs[kk][tx * 4]);
            float a[4] = {av.x, av.y, av.z, av.w};
            float bb[4] = {bv.x, bv.y, bv.z, bv.w};
#pragma unroll
            for (int i = 0; i < 4; ++i)
#pragma unroll
                for (int j = 0; j < 4; ++j) acc[i][j] += a[i] * bb[j];
        }
        __syncthreads();
    }
#pragma unroll
    for (int i = 0; i < 4; ++i) {
        int row = tM + ty * 4 + i;
        int b = row >> 10, n = row & 1023;
#pragma unroll
        for (int j = 0; j < 4; ++j) {
            int col = tN + tx * 4 + j;
            int three = col / 768;
            int r = col % 768;
            int h = r >> 6, d = r & 63;
            size_t idx = (((size_t)(b * HEADS + h) << 10) + n) * HD + d;
            if (three == 0)      q[idx] = __float2bfloat16(acc[i][j] * 0.125f);  // fold scale
            else if (three == 1) k[idx] = __float2bfloat16(acc[i][j]);
            else                 v[idx] = __float2bfloat16(acc[i][j]);
        }
    }
}

// ---------------------------------------------------------------------------
// Kernel 2: MFMA QK^T -> per-row o = m + log l (sweep 1, chunk-online) and
// coarse LDS histogram of t = s - o (sweep 2, identical recompute).
// Block = 64 q-rows of one (b,h); 4 waves x 16 rows.
// ---------------------------------------------------------------------------
__global__ __launch_bounds__(256) void stats_mfma(const short* __restrict__ q,
                                                  const short* __restrict__ k,
                                                  float* __restrict__ orow,
                                                  unsigned* __restrict__ hist) {
    __shared__ short kls[8192];            // [128][64] bf16, XOR-swizzled rows
    __shared__ unsigned hl[2 * NB1];       // 2 copies to halve same-bin contention
    int bid = blockIdx.x;
    int grp = bid & 15;
    int bh = bid >> 4;
    int b = bh / HEADS;
    int tid = threadIdx.x, wave = tid >> 6, lane = tid & 63;
    int lg = lane >> 4, lc = lane & 15;
    const short* kbase = k + (size_t)bh * SEQ * HD;
    int qrow0 = grp * 64 + wave * 16;
    const short* qbase = q + ((size_t)bh * SEQ + qrow0) * HD;
    bf16x8 qf0 = *(const bf16x8*)&qbase[lc * 64 + lg * 8];
    bf16x8 qf1 = *(const bf16x8*)&qbase[lc * 64 + 32 + lg * 8];

    for (int i = tid; i < 2 * NB1; i += 256) hl[i] = 0;

    float m[4] = {-1e30f, -1e30f, -1e30f, -1e30f};
    float lsum[4] = {0.f, 0.f, 0.f, 0.f};

    auto stage = [&](int c) {
#pragma unroll
        for (int j = 0; j < 4; ++j) {
            int r = j * 32 + (tid >> 3);
            int col = (tid & 7) * 8;
            bf16x8 d = *(const bf16x8*)&kbase[(size_t)(c * 128 + r) * 64 + col];
            *(bf16x8*)&kls[r * 64 + (col ^ ((r & 7) << 3))] = d;
        }
    };

    // ---- sweep 1: running (m, l) with per-chunk rescale ----
    for (int c = 0; c < 8; ++c) {
        __syncthreads();
        stage(c);
        __syncthreads();
        f32x4 sv[8];
#pragma unroll
        for (int t = 0; t < 8; ++t) {
            int krow = t * 16 + lc;
            int sw = (krow & 7) << 3;
            bf16x8 b0 = *(bf16x8*)&kls[krow * 64 + ((lg * 8) ^ sw)];
            bf16x8 b1 = *(bf16x8*)&kls[krow * 64 + ((32 + lg * 8) ^ sw)];
            f32x4 acc = {};
            acc = MFMA16(qf0, b0, acc);
            acc = MFMA16(qf1, b1, acc);
            sv[t] = acc;
        }
#pragma unroll
        for (int r = 0; r < 4; ++r) {
            float cmax = sv[0][r];
#pragma unroll
            for (int t = 1; t < 8; ++t) cmax = fmaxf(cmax, sv[t][r]);
            float nm = fmaxf(m[r], cmax);
            float s = 0.f;
#pragma unroll
            for (int t = 0; t < 8; ++t) s += __expf(sv[t][r] - nm);
            lsum[r] = lsum[r] * __expf(m[r] - nm) + s;
            m[r] = nm;
        }
    }
    // merge across the 16 lanes sharing each row (xor over lc bits)
    float o[4];
#pragma unroll
    for (int r = 0; r < 4; ++r) {
#pragma unroll
        for (int off = 1; off < 16; off <<= 1) {
            float mo = __shfl_xor(m[r], off, 64);
            float lo = __shfl_xor(lsum[r], off, 64);
            float nm = fmaxf(m[r], mo);
            lsum[r] = lsum[r] * __expf(m[r] - nm) + lo * __expf(mo - nm);
            m[r] = nm;
        }
        o[r] = m[r] + __logf(lsum[r]);
        if (lc == 0) orow[(size_t)bh * SEQ + qrow0 + lg * 4 + r] = o[r];
    }

    // ---- sweep 2: identical recompute -> histogram ----
    for (int c = 0; c < 8; ++c) {
        __syncthreads();
        stage(c);
        __syncthreads();
#pragma unroll
        for (int t = 0; t < 8; ++t) {
            int krow = t * 16 + lc;
            int sw = (krow & 7) << 3;
            bf16x8 b0 = *(bf16x8*)&kls[krow * 64 + ((lg * 8) ^ sw)];
            bf16x8 b1 = *(bf16x8*)&kls[krow * 64 + ((32 + lg * 8) ^ sw)];
            f32x4 acc = {};
            acc = MFMA16(qf0, b0, acc);
            acc = MFMA16(qf1, b1, acc);
#pragma unroll
            for (int r = 0; r < 4; ++r) {
                float tv = acc[r] - o[r];
                int bin = (int)((tv - TMIN1) * 256.0f);
                bin = bin < 0 ? 0 : (bin > NB1 - 1 ? NB1 - 1 : bin);
                atomicAdd(&hl[((lane & 1) << 12) + bin], 1u);
            }
        }
    }
    __syncthreads();
    unsigned* hb = hist + (size_t)b * NB1;
    for (int i = tid; i < NB1; i += 256) {
        unsigned s = hl[i] + hl[NB1 + i];
        if (s) atomicAdd(&hb[i], s);
    }
}

// ---------------------------------------------------------------------------
// Kernel 3: per-batch threshold = lower edge of bin holding k-th largest
// ---------------------------------------------------------------------------
__global__ __launch_bounds__(256) void find_thr(const unsigned* __restrict__ hist,
                                                float* __restrict__ thr) {
    __shared__ unsigned cs[256];
    int b = blockIdx.x, tid = threadIdx.x;
    const unsigned* hb = hist + (size_t)b * NB1;
    unsigned s = 0;
#pragma unroll
    for (int i = 0; i < 16; ++i) s += hb[tid * 16 + i];
    cs[tid] = s;
    __syncthreads();
    unsigned suf = 0;
    for (int j = tid; j < 256; ++j) suf += cs[j];
    unsigned above = suf - cs[tid];
    if (suf >= K_NEED && above < K_NEED) {
        unsigned acc = above;
        for (int bb = 15; bb >= 0; --bb) {
            acc += hb[tid * 16 + bb];
            if (acc >= K_NEED) {
                thr[b] = TMIN1 + (float)(tid * 16 + bb) * WC;
                break;
            }
        }
    }
}

// ---------------------------------------------------------------------------
// Kernel 4: MFMA recompute S (identical), mask t>=thr, P=exp(t) bf16 -> PV.
// ---------------------------------------------------------------------------
__global__ __launch_bounds__(256) void pv_mfma(const short* __restrict__ q,
                                               const short* __restrict__ k,
                                               const short* __restrict__ v,
                                               const float* __restrict__ orow,
                                               const float* __restrict__ thr,
                                               float* __restrict__ aout) {
    __shared__ short kls[8192];        // K chunk [128][64], swizzled
    __shared__ short vls[8192];        // V^T chunk [64][128], swizzled
    __shared__ short pls[4][2048];     // per-wave P [16][128], swizzled
    int bid = blockIdx.x;
    int grp = bid & 15;
    int bh = bid >> 4;
    int b = bh / HEADS, h = bh % HEADS;
    int tid = threadIdx.x, wave = tid >> 6, lane = tid & 63;
    int lg = lane >> 4, lc = lane & 15;
    const short* kbase = k + (size_t)bh * SEQ * HD;
    const short* vbase = v + (size_t)bh * SEQ * HD;
    int qrow0 = grp * 64 + wave * 16;
    const short* qbase = q + ((size_t)bh * SEQ + qrow0) * HD;
    bf16x8 qf0 = *(const bf16x8*)&qbase[lc * 64 + lg * 8];
    bf16x8 qf1 = *(const bf16x8*)&qbase[lc * 64 + 32 + lg * 8];
    float o[4];
#pragma unroll
    for (int r = 0; r < 4; ++r) o[r] = orow[(size_t)bh * SEQ + qrow0 + lg * 4 + r];
    float tt = thr[b];
    f32x4 oacc[4] = {};
    short* pw = pls[wave];

    for (int c = 0; c < 8; ++c) {
        __syncthreads();
        // stage K (coalesced read, swizzled b128 LDS write)
#pragma unroll
        for (int j = 0; j < 4; ++j) {
            int r = j * 32 + (tid >> 3);
            int col = (tid & 7) * 8;
            bf16x8 d = *(const bf16x8*)&kbase[(size_t)(c * 128 + r) * 64 + col];
            *(bf16x8*)&kls[r * 64 + (col ^ ((r & 7) << 3))] = d;
        }
        // stage V transposed: vls[dv][kj]
        {
            int kj = tid >> 1;
#pragma unroll
            for (int j = 0; j < 4; ++j) {
                int dv0 = (tid & 1) * 32 + j * 8;
                bf16x8 d = *(const bf16x8*)&vbase[(size_t)(c * 128 + kj) * 64 + dv0];
#pragma unroll
                for (int i = 0; i < 8; ++i) {
                    int dv = dv0 + i;
                    vls[dv * 128 + (kj ^ ((dv & 7) << 3))] = d[i];
                }
            }
        }
        __syncthreads();
        // QK^T tiles -> masked P (bf16, per-wave LDS)
#pragma unroll
        for (int t = 0; t < 8; ++t) {
            int krow = t * 16 + lc;
            int sw = (krow & 7) << 3;
            bf16x8 b0 = *(bf16x8*)&kls[krow * 64 + ((lg * 8) ^ sw)];
            bf16x8 b1 = *(bf16x8*)&kls[krow * 64 + ((32 + lg * 8) ^ sw)];
            f32x4 acc = {};
            acc = MFMA16(qf0, b0, acc);
            acc = MFMA16(qf1, b1, acc);
#pragma unroll
            for (int r = 0; r < 4; ++r) {
                float tv = acc[r] - o[r];
                float p = (tv >= tt) ? __expf(tv) : 0.f;
                int prow = lg * 4 + r;
                int pcol = t * 16 + lc;
                *(__hip_bfloat16*)&pw[prow * 128 + (pcol ^ ((prow & 7) << 3))] = __float2bfloat16(p);
            }
        }
        // PV: out[16 q][64 dv] += P[16][128] x V[128][64]
#pragma unroll
        for (int dt = 0; dt < 4; ++dt) {
#pragma unroll
            for (int kb = 0; kb < 4; ++kb) {
                int pcol = kb * 32 + lg * 8;
                bf16x8 pa = *(bf16x8*)&pw[lc * 128 + (pcol ^ ((lc & 7) << 3))];
                int vrow = dt * 16 + lc;
                bf16x8 vfrag = *(bf16x8*)&vls[vrow * 128 + (pcol ^ ((vrow & 7) << 3))];
                oacc[dt] = MFMA16(pa, vfrag, oacc[dt]);
            }
        }
    }
#pragma unroll
    for (int dt = 0; dt < 4; ++dt)
#pragma unroll
        for (int r = 0; r < 4; ++r)
            aout[((size_t)b * SEQ + qrow0 + lg * 4 + r) * CDIM + h * 64 + dt * 16 + lc] = oacc[dt][r];
}

// ---------------------------------------------------------------------------
// Kernel 5: out = aout @ W_proj + b_proj + origin (fp32)
// ---------------------------------------------------------------------------
__global__ __launch_bounds__(256) void proj_gemm(const float* __restrict__ A,
                                                 const float* __restrict__ W,
                                                 const float* __restrict__ bias,
                                                 const float* __restrict__ origin,
                                                 float* __restrict__ out) {
    const int K = 768, NN = 768;
    int tM = blockIdx.x * 64;
    int tN = blockIdx.y * 64;
    __shared__ float As[16][68];
    __shared__ float Bs[16][68];
    int tid = threadIdx.x;
    int tx = tid & 15, ty = tid >> 4;
    float acc[4][4] = {};
    for (int k0 = 0; k0 < K; k0 += 16) {
        {
            int r = tid >> 2, c4 = (tid & 3) * 4;
            float4 a = *reinterpret_cast<const float4*>(&A[(size_t)(tM + r) * K + k0 + c4]);
            As[c4 + 0][r] = a.x; As[c4 + 1][r] = a.y; As[c4 + 2][r] = a.z; As[c4 + 3][r] = a.w;
        }
        {
            int r = tid >> 4, c4 = (tid & 15) * 4;
            float4 bv = *reinterpret_cast<const float4*>(&W[(size_t)(k0 + r) * NN + tN + c4]);
            *reinterpret_cast<float4*>(&Bs[r][c4]) = bv;
        }
        __syncthreads();
#pragma unroll
        for (int kk = 0; kk < 16; ++kk) {
            float4 av = *reinterpret_cast<const float4*>(&As[kk][ty * 4]);
            float4 bv = *reinterpret_cast<const float4*>(&Bs[kk][tx * 4]);
            float a[4] = {av.x, av.y, av.z, av.w};
            float bb[4] = {bv.x, bv.y, bv.z, bv.w};
#pragma unroll
            for (int i = 0; i < 4; ++i)
#pragma unroll
                for (int j = 0; j < 4; ++j) acc[i][j] += a[i] * bb[j];
        }
        __syncthreads();
    }
#pragma unroll
    for (int i = 0; i < 4; ++i) {
        int row = tM + ty * 4 + i;
#pragma unroll
        for (int j = 0; j < 4; ++j) {
            int col = tN + tx * 4 + j;
            out[(size_t)row * NN + col] = acc[i][j] + bias[col] + origin[(size_t)row * NN + col];
        }
    }
}

// ---------------------------------------------------------------------------
extern "C" void kernel_launch(void* const* d_in, const int* in_sizes, int n_in,
                              void* d_out, int out_size, void* d_ws, size_t ws_size,
                              hipStream_t stream) {
    const float* x      = (const float*)d_in[0];
    const float* origin = (const float*)d_in[1];
    const float* W_qkv  = (const float*)d_in[2];
    const float* W_proj = (const float*)d_in[3];
    const float* b_proj = (const float*)d_in[4];
    float* out = (float*)d_out;
    float* ws = (float*)d_ws;

    const size_t QKV_ELEMS = (size_t)BATCH * HEADS * SEQ * HD;  // 6291456
    size_t off = 0;  // in floats
    __hip_bfloat16* q = (__hip_bfloat16*)(ws + off); off += QKV_ELEMS / 2;
    __hip_bfloat16* k = (__hip_bfloat16*)(ws + off); off += QKV_ELEMS / 2;
    __hip_bfloat16* v = (__hip_bfloat16*)(ws + off); off += QKV_ELEMS / 2;
    float* orow = ws + off; off += (size_t)BATCH * HEADS * SEQ;   // 98304
    float* thr = ws + off;  off += 8;
    unsigned* hist = (unsigned*)(ws + off); off += (size_t)BATCH * NB1;
    float* aout = ws + off; off += QKV_ELEMS;

    hipMemsetAsync(hist, 0, (size_t)BATCH * NB1 * sizeof(unsigned), stream);
    qkv_gemm<<<dim3(128, 36), 256, 0, stream>>>(x, W_qkv, q, k, v);
    stats_mfma<<<dim3(BATCH * HEADS * 16), 256, 0, stream>>>((const short*)q, (const short*)k, orow, hist);
    find_thr<<<dim3(BATCH), 256, 0, stream>>>(hist, thr);
    pv_mfma<<<dim3(BATCH * HEADS * 16), 256, 0, stream>>>((const short*)q, (const short*)k, (const short*)v,
                                                          orow, thr, aout);
    proj_gemm<<<dim3(128, 12), 256, 0, stream>>>(aout, W_proj, b_proj, origin, out);
}

// Round 4
// 246.389 us; speedup vs baseline: 32.1802x; 2.8040x over previous
//
#include <hip/hip_runtime.h>
#include <hip/hip_bf16.h>

// Problem constants
#define BATCH 8
#define SEQ   1024
#define CDIM  768
#define HEADS 12
#define HD    64

// Coarse histogram: 4096 bins over t = s - o in [-16, 0], width 1/256.
#define NB1    4096
#define TMIN1  (-16.0f)
#define WC     (1.0f / 256.0f)
#define K_NEED 2516582u   // int(12*1024*1024*0.2)

typedef __attribute__((ext_vector_type(8))) short bf16x8;   // 8 bf16 = 4 VGPR
typedef __attribute__((ext_vector_type(4))) float f32x4;

#define MFMA16(a, b, c) __builtin_amdgcn_mfma_f32_16x16x32_bf16(a, b, c, 0, 0, 0)

// ---------------------------------------------------------------------------
// Prep A: x fp32 -> bf16 (flat)
// ---------------------------------------------------------------------------
__global__ __launch_bounds__(256) void convert_x(const float* __restrict__ in,
                                                 short* __restrict__ out, int n8) {
    int i = blockIdx.x * 256 + threadIdx.x;
    if (i >= n8) return;
    float4 a = *reinterpret_cast<const float4*>(&in[(size_t)i * 8]);
    float4 b = *reinterpret_cast<const float4*>(&in[(size_t)i * 8 + 4]);
    __hip_bfloat16 tmp[8];
    tmp[0] = __float2bfloat16(a.x); tmp[1] = __float2bfloat16(a.y);
    tmp[2] = __float2bfloat16(a.z); tmp[3] = __float2bfloat16(a.w);
    tmp[4] = __float2bfloat16(b.x); tmp[5] = __float2bfloat16(b.y);
    tmp[6] = __float2bfloat16(b.z); tmp[7] = __float2bfloat16(b.w);
    *reinterpret_cast<bf16x8*>(&out[(size_t)i * 8]) = *reinterpret_cast<bf16x8*>(tmp);
}

// ---------------------------------------------------------------------------
// Prep B: W [768][C] fp32 -> W^T [C][768] bf16
// ---------------------------------------------------------------------------
__global__ __launch_bounds__(256) void transpose_w(const float* __restrict__ in,
                                                   short* __restrict__ out, int C) {
    __shared__ float ls[64][68];
    int r0 = blockIdx.x * 64, c0 = blockIdx.y * 64;
    int tid = threadIdx.x;
#pragma unroll
    for (int it = 0; it < 4; ++it) {
        int rr = it * 16 + (tid >> 4);
        int cc = (tid & 15) * 4;
        float4 d = *reinterpret_cast<const float4*>(&in[(size_t)(r0 + rr) * C + c0 + cc]);
        ls[rr][cc + 0] = d.x; ls[rr][cc + 1] = d.y; ls[rr][cc + 2] = d.z; ls[rr][cc + 3] = d.w;
    }
    __syncthreads();
#pragma unroll
    for (int it = 0; it < 2; ++it) {
        int orow = it * 32 + (tid >> 3);   // local column index of input
        int oc = (tid & 7) * 8;            // local row index of input
        __hip_bfloat16 tmp[8];
#pragma unroll
        for (int j = 0; j < 8; ++j) tmp[j] = __float2bfloat16(ls[oc + j][orow]);
        *reinterpret_cast<bf16x8*>(&out[(size_t)(c0 + orow) * 768 + r0 + oc]) =
            *reinterpret_cast<bf16x8*>(tmp);
    }
}

// ---------------------------------------------------------------------------
// Kernel 1: qkv = xb @ Wqt^T via MFMA. 128x128 tile, 4 waves, BK=64.
// Epilogue scatters bf16 q (x0.125), k, v.
// ---------------------------------------------------------------------------
__global__ __launch_bounds__(256) void qkv_mfma(const short* __restrict__ A,   // [8192][768]
                                                const short* __restrict__ Bt,  // [2304][768]
                                                __hip_bfloat16* __restrict__ q,
                                                __hip_bfloat16* __restrict__ k,
                                                __hip_bfloat16* __restrict__ v) {
    const int K = 768;
    __shared__ short As[128 * 64];
    __shared__ short Bs[128 * 64];
    int tM = blockIdx.x * 128, tN = blockIdx.y * 128;
    int tid = threadIdx.x, wave = tid >> 6, lane = tid & 63, lg = lane >> 4, lc = lane & 15;
    int wr = wave >> 1, wc = wave & 1;
    f32x4 acc[4][4] = {};
    for (int kc = 0; kc < K; kc += 64) {
        __syncthreads();
#pragma unroll
        for (int j = 0; j < 4; ++j) {
            int r = j * 32 + (tid >> 3);
            int col = (tid & 7) * 8;
            int sw = col ^ ((r & 7) << 3);
            *(bf16x8*)&As[r * 64 + sw] = *(const bf16x8*)&A[(size_t)(tM + r) * K + kc + col];
            *(bf16x8*)&Bs[r * 64 + sw] = *(const bf16x8*)&Bt[(size_t)(tN + r) * K + kc + col];
        }
        __syncthreads();
        bf16x8 af[4][2], bfr[4][2];
#pragma unroll
        for (int m4 = 0; m4 < 4; ++m4) {
            int r = wr * 64 + m4 * 16 + lc;
            int sw = (r & 7) << 3;
            af[m4][0] = *(bf16x8*)&As[r * 64 + ((lg * 8) ^ sw)];
            af[m4][1] = *(bf16x8*)&As[r * 64 + ((32 + lg * 8) ^ sw)];
        }
#pragma unroll
        for (int n4 = 0; n4 < 4; ++n4) {
            int r = wc * 64 + n4 * 16 + lc;
            int sw = (r & 7) << 3;
            bfr[n4][0] = *(bf16x8*)&Bs[r * 64 + ((lg * 8) ^ sw)];
            bfr[n4][1] = *(bf16x8*)&Bs[r * 64 + ((32 + lg * 8) ^ sw)];
        }
#pragma unroll
        for (int m4 = 0; m4 < 4; ++m4)
#pragma unroll
            for (int n4 = 0; n4 < 4; ++n4) {
                acc[m4][n4] = MFMA16(af[m4][0], bfr[n4][0], acc[m4][n4]);
                acc[m4][n4] = MFMA16(af[m4][1], bfr[n4][1], acc[m4][n4]);
            }
    }
    int three = tN / 768;                 // uniform per block (768 = 6*128)
    __hip_bfloat16* dst = (three == 0) ? q : (three == 1) ? k : v;
    float mult = (three == 0) ? 0.125f : 1.0f;
    int cbase = tN - three * 768 + wc * 64;
#pragma unroll
    for (int m4 = 0; m4 < 4; ++m4)
#pragma unroll
        for (int n4 = 0; n4 < 4; ++n4)
#pragma unroll
            for (int r = 0; r < 4; ++r) {
                int row = tM + wr * 64 + m4 * 16 + lg * 4 + r;
                int b = row >> 10, n = row & 1023;
                int cw = cbase + n4 * 16 + lc;
                int h = cw >> 6, d = cw & 63;
                dst[(((size_t)(b * HEADS + h) << 10) + n) * HD + d] =
                    __float2bfloat16(acc[m4][n4][r] * mult);
            }
}

// ---------------------------------------------------------------------------
// Kernel 2: MFMA QK^T -> per-row o = m + log l and coarse LDS histogram.
// ---------------------------------------------------------------------------
__global__ __launch_bounds__(256) void stats_mfma(const short* __restrict__ q,
                                                  const short* __restrict__ k,
                                                  float* __restrict__ orow,
                                                  unsigned* __restrict__ hist) {
    __shared__ short kls[8192];            // [128][64] bf16, XOR-swizzled rows
    __shared__ unsigned hl[2 * NB1];
    int bid = blockIdx.x;
    int grp = bid & 15;
    int bh = bid >> 4;
    int b = bh / HEADS;
    int tid = threadIdx.x, wave = tid >> 6, lane = tid & 63;
    int lg = lane >> 4, lc = lane & 15;
    const short* kbase = k + (size_t)bh * SEQ * HD;
    int qrow0 = grp * 64 + wave * 16;
    const short* qbase = q + ((size_t)bh * SEQ + qrow0) * HD;
    bf16x8 qf0 = *(const bf16x8*)&qbase[lc * 64 + lg * 8];
    bf16x8 qf1 = *(const bf16x8*)&qbase[lc * 64 + 32 + lg * 8];

    for (int i = tid; i < 2 * NB1; i += 256) hl[i] = 0;

    float m[4] = {-1e30f, -1e30f, -1e30f, -1e30f};
    float lsum[4] = {0.f, 0.f, 0.f, 0.f};

    auto stage = [&](int c) {
#pragma unroll
        for (int j = 0; j < 4; ++j) {
            int r = j * 32 + (tid >> 3);
            int col = (tid & 7) * 8;
            bf16x8 d = *(const bf16x8*)&kbase[(size_t)(c * 128 + r) * 64 + col];
            *(bf16x8*)&kls[r * 64 + (col ^ ((r & 7) << 3))] = d;
        }
    };

    for (int c = 0; c < 8; ++c) {
        __syncthreads();
        stage(c);
        __syncthreads();
        f32x4 sv[8];
#pragma unroll
        for (int t = 0; t < 8; ++t) {
            int krow = t * 16 + lc;
            int sw = (krow & 7) << 3;
            bf16x8 b0 = *(bf16x8*)&kls[krow * 64 + ((lg * 8) ^ sw)];
            bf16x8 b1 = *(bf16x8*)&kls[krow * 64 + ((32 + lg * 8) ^ sw)];
            f32x4 acc = {};
            acc = MFMA16(qf0, b0, acc);
            acc = MFMA16(qf1, b1, acc);
            sv[t] = acc;
        }
#pragma unroll
        for (int r = 0; r < 4; ++r) {
            float cmax = sv[0][r];
#pragma unroll
            for (int t = 1; t < 8; ++t) cmax = fmaxf(cmax, sv[t][r]);
            float nm = fmaxf(m[r], cmax);
            float s = 0.f;
#pragma unroll
            for (int t = 0; t < 8; ++t) s += __expf(sv[t][r] - nm);
            lsum[r] = lsum[r] * __expf(m[r] - nm) + s;
            m[r] = nm;
        }
    }
    float o[4];
#pragma unroll
    for (int r = 0; r < 4; ++r) {
#pragma unroll
        for (int off = 1; off < 16; off <<= 1) {
            float mo = __shfl_xor(m[r], off, 64);
            float lo = __shfl_xor(lsum[r], off, 64);
            float nm = fmaxf(m[r], mo);
            lsum[r] = lsum[r] * __expf(m[r] - nm) + lo * __expf(mo - nm);
            m[r] = nm;
        }
        o[r] = m[r] + __logf(lsum[r]);
        if (lc == 0) orow[(size_t)bh * SEQ + qrow0 + lg * 4 + r] = o[r];
    }

    for (int c = 0; c < 8; ++c) {
        __syncthreads();
        stage(c);
        __syncthreads();
#pragma unroll
        for (int t = 0; t < 8; ++t) {
            int krow = t * 16 + lc;
            int sw = (krow & 7) << 3;
            bf16x8 b0 = *(bf16x8*)&kls[krow * 64 + ((lg * 8) ^ sw)];
            bf16x8 b1 = *(bf16x8*)&kls[krow * 64 + ((32 + lg * 8) ^ sw)];
            f32x4 acc = {};
            acc = MFMA16(qf0, b0, acc);
            acc = MFMA16(qf1, b1, acc);
#pragma unroll
            for (int r = 0; r < 4; ++r) {
                float tv = acc[r] - o[r];
                int bin = (int)((tv - TMIN1) * 256.0f);
                bin = bin < 0 ? 0 : (bin > NB1 - 1 ? NB1 - 1 : bin);
                atomicAdd(&hl[((lane & 1) << 12) + bin], 1u);
            }
        }
    }
    __syncthreads();
    unsigned* hb = hist + (size_t)b * NB1;
    for (int i = tid; i < NB1; i += 256) {
        unsigned s = hl[i] + hl[NB1 + i];
        if (s) atomicAdd(&hb[i], s);
    }
}

// ---------------------------------------------------------------------------
// Kernel 3: per-batch threshold = lower edge of bin holding k-th largest
// ---------------------------------------------------------------------------
__global__ __launch_bounds__(256) void find_thr(const unsigned* __restrict__ hist,
                                                float* __restrict__ thr) {
    __shared__ unsigned cs[256];
    int b = blockIdx.x, tid = threadIdx.x;
    const unsigned* hb = hist + (size_t)b * NB1;
    unsigned s = 0;
#pragma unroll
    for (int i = 0; i < 16; ++i) s += hb[tid * 16 + i];
    cs[tid] = s;
    __syncthreads();
    unsigned suf = 0;
    for (int j = tid; j < 256; ++j) suf += cs[j];
    unsigned above = suf - cs[tid];
    if (suf >= K_NEED && above < K_NEED) {
        unsigned acc = above;
        for (int bb = 15; bb >= 0; --bb) {
            acc += hb[tid * 16 + bb];
            if (acc >= K_NEED) {
                thr[b] = TMIN1 + (float)(tid * 16 + bb) * WC;
                break;
            }
        }
    }
}

// ---------------------------------------------------------------------------
// Kernel 4: MFMA recompute S, mask t>=thr, P=exp(t) bf16 -> PV. Writes bf16 aout.
// ---------------------------------------------------------------------------
__global__ __launch_bounds__(256) void pv_mfma(const short* __restrict__ q,
                                               const short* __restrict__ k,
                                               const short* __restrict__ v,
                                               const float* __restrict__ orow,
                                               const float* __restrict__ thr,
                                               __hip_bfloat16* __restrict__ aout) {
    __shared__ short kls[8192];        // K chunk [128][64], swizzled
    __shared__ short vls[8192];        // V^T chunk [64][128], swizzled
    __shared__ short pls[4][2048];     // per-wave P [16][128], swizzled
    int bid = blockIdx.x;
    int grp = bid & 15;
    int bh = bid >> 4;
    int b = bh / HEADS, h = bh % HEADS;
    int tid = threadIdx.x, wave = tid >> 6, lane = tid & 63;
    int lg = lane >> 4, lc = lane & 15;
    const short* kbase = k + (size_t)bh * SEQ * HD;
    const short* vbase = v + (size_t)bh * SEQ * HD;
    int qrow0 = grp * 64 + wave * 16;
    const short* qbase = q + ((size_t)bh * SEQ + qrow0) * HD;
    bf16x8 qf0 = *(const bf16x8*)&qbase[lc * 64 + lg * 8];
    bf16x8 qf1 = *(const bf16x8*)&qbase[lc * 64 + 32 + lg * 8];
    float o[4];
#pragma unroll
    for (int r = 0; r < 4; ++r) o[r] = orow[(size_t)bh * SEQ + qrow0 + lg * 4 + r];
    float tt = thr[b];
    f32x4 oacc[4] = {};
    short* pw = pls[wave];

    for (int c = 0; c < 8; ++c) {
        __syncthreads();
#pragma unroll
        for (int j = 0; j < 4; ++j) {
            int r = j * 32 + (tid >> 3);
            int col = (tid & 7) * 8;
            bf16x8 d = *(const bf16x8*)&kbase[(size_t)(c * 128 + r) * 64 + col];
            *(bf16x8*)&kls[r * 64 + (col ^ ((r & 7) << 3))] = d;
        }
        {
            int kj = tid >> 1;
#pragma unroll
            for (int j = 0; j < 4; ++j) {
                int dv0 = (tid & 1) * 32 + j * 8;
                bf16x8 d = *(const bf16x8*)&vbase[(size_t)(c * 128 + kj) * 64 + dv0];
#pragma unroll
                for (int i = 0; i < 8; ++i) {
                    int dv = dv0 + i;
                    vls[dv * 128 + (kj ^ ((dv & 7) << 3))] = d[i];
                }
            }
        }
        __syncthreads();
#pragma unroll
        for (int t = 0; t < 8; ++t) {
            int krow = t * 16 + lc;
            int sw = (krow & 7) << 3;
            bf16x8 b0 = *(bf16x8*)&kls[krow * 64 + ((lg * 8) ^ sw)];
            bf16x8 b1 = *(bf16x8*)&kls[krow * 64 + ((32 + lg * 8) ^ sw)];
            f32x4 acc = {};
            acc = MFMA16(qf0, b0, acc);
            acc = MFMA16(qf1, b1, acc);
#pragma unroll
            for (int r = 0; r < 4; ++r) {
                float tv = acc[r] - o[r];
                float p = (tv >= tt) ? __expf(tv) : 0.f;
                int prow = lg * 4 + r;
                int pcol = t * 16 + lc;
                *(__hip_bfloat16*)&pw[prow * 128 + (pcol ^ ((prow & 7) << 3))] = __float2bfloat16(p);
            }
        }
#pragma unroll
        for (int dt = 0; dt < 4; ++dt) {
#pragma unroll
            for (int kb = 0; kb < 4; ++kb) {
                int pcol = kb * 32 + lg * 8;
                bf16x8 pa = *(bf16x8*)&pw[lc * 128 + (pcol ^ ((lc & 7) << 3))];
                int vrow = dt * 16 + lc;
                bf16x8 vfrag = *(bf16x8*)&vls[vrow * 128 + (pcol ^ ((vrow & 7) << 3))];
                oacc[dt] = MFMA16(pa, vfrag, oacc[dt]);
            }
        }
    }
#pragma unroll
    for (int dt = 0; dt < 4; ++dt)
#pragma unroll
        for (int r = 0; r < 4; ++r)
            aout[((size_t)b * SEQ + qrow0 + lg * 4 + r) * CDIM + h * 64 + dt * 16 + lc] =
                __float2bfloat16(oacc[dt][r]);
}

// ---------------------------------------------------------------------------
// Kernel 5: out = aoutb @ Wpt^T + b_proj + origin (MFMA, fp32 epilogue)
// ---------------------------------------------------------------------------
__global__ __launch_bounds__(256) void proj_mfma(const short* __restrict__ A,   // [8192][768]
                                                 const short* __restrict__ Bt,  // [768][768]
                                                 const float* __restrict__ bias,
                                                 const float* __restrict__ origin,
                                                 float* __restrict__ out) {
    const int K = 768, NN = 768;
    __shared__ short As[128 * 64];
    __shared__ short Bs[128 * 64];
    int tM = blockIdx.x * 128, tN = blockIdx.y * 128;
    int tid = threadIdx.x, wave = tid >> 6, lane = tid & 63, lg = lane >> 4, lc = lane & 15;
    int wr = wave >> 1, wc = wave & 1;
    f32x4 acc[4][4] = {};
    for (int kc = 0; kc < K; kc += 64) {
        __syncthreads();
#pragma unroll
        for (int j = 0; j < 4; ++j) {
            int r = j * 32 + (tid >> 3);
            int col = (tid & 7) * 8;
            int sw = col ^ ((r & 7) << 3);
            *(bf16x8*)&As[r * 64 + sw] = *(const bf16x8*)&A[(size_t)(tM + r) * K + kc + col];
            *(bf16x8*)&Bs[r * 64 + sw] = *(const bf16x8*)&Bt[(size_t)(tN + r) * K + kc + col];
        }
        __syncthreads();
        bf16x8 af[4][2], bfr[4][2];
#pragma unroll
        for (int m4 = 0; m4 < 4; ++m4) {
            int r = wr * 64 + m4 * 16 + lc;
            int sw = (r & 7) << 3;
            af[m4][0] = *(bf16x8*)&As[r * 64 + ((lg * 8) ^ sw)];
            af[m4][1] = *(bf16x8*)&As[r * 64 + ((32 + lg * 8) ^ sw)];
        }
#pragma unroll
        for (int n4 = 0; n4 < 4; ++n4) {
            int r = wc * 64 + n4 * 16 + lc;
            int sw = (r & 7) << 3;
            bfr[n4][0] = *(bf16x8*)&Bs[r * 64 + ((lg * 8) ^ sw)];
            bfr[n4][1] = *(bf16x8*)&Bs[r * 64 + ((32 + lg * 8) ^ sw)];
        }
#pragma unroll
        for (int m4 = 0; m4 < 4; ++m4)
#pragma unroll
            for (int n4 = 0; n4 < 4; ++n4) {
                acc[m4][n4] = MFMA16(af[m4][0], bfr[n4][0], acc[m4][n4]);
                acc[m4][n4] = MFMA16(af[m4][1], bfr[n4][1], acc[m4][n4]);
            }
    }
#pragma unroll
    for (int m4 = 0; m4 < 4; ++m4)
#pragma unroll
        for (int n4 = 0; n4 < 4; ++n4)
#pragma unroll
            for (int r = 0; r < 4; ++r) {
                int row = tM + wr * 64 + m4 * 16 + lg * 4 + r;
                int col = tN + wc * 64 + n4 * 16 + lc;
                out[(size_t)row * NN + col] = acc[m4][n4][r] + bias[col] + origin[(size_t)row * NN + col];
            }
}

// ---------------------------------------------------------------------------
extern "C" void kernel_launch(void* const* d_in, const int* in_sizes, int n_in,
                              void* d_out, int out_size, void* d_ws, size_t ws_size,
                              hipStream_t stream) {
    const float* x      = (const float*)d_in[0];
    const float* origin = (const float*)d_in[1];
    const float* W_qkv  = (const float*)d_in[2];
    const float* W_proj = (const float*)d_in[3];
    const float* b_proj = (const float*)d_in[4];
    float* out = (float*)d_out;
    char* ws = (char*)d_ws;

    const size_t QKV_ELEMS = (size_t)BATCH * HEADS * SEQ * HD;   // 6291456
    const size_t X_ELEMS   = (size_t)BATCH * SEQ * CDIM;         // 6291456
    size_t off = 0;
    short* xb  = (short*)(ws + off); off += X_ELEMS * 2;
    short* wqt = (short*)(ws + off); off += (size_t)2304 * 768 * 2;
    short* wpt = (short*)(ws + off); off += (size_t)768 * 768 * 2;
    short* q   = (short*)(ws + off); off += QKV_ELEMS * 2;
    short* k   = (short*)(ws + off); off += QKV_ELEMS * 2;
    short* v   = (short*)(ws + off); off += QKV_ELEMS * 2;
    short* aoutb = (short*)(ws + off); off += QKV_ELEMS * 2;
    float* orow = (float*)(ws + off); off += (size_t)BATCH * HEADS * SEQ * 4;
    unsigned* hist = (unsigned*)(ws + off); off += (size_t)BATCH * NB1 * 4;
    float* thr = (float*)(ws + off); off += 8 * 4;

    hipMemsetAsync(hist, 0, (size_t)BATCH * NB1 * sizeof(unsigned), stream);
    convert_x<<<dim3((X_ELEMS / 8 + 255) / 256), 256, 0, stream>>>(x, xb, (int)(X_ELEMS / 8));
    transpose_w<<<dim3(12, 36), 256, 0, stream>>>(W_qkv, wqt, 2304);
    transpose_w<<<dim3(12, 12), 256, 0, stream>>>(W_proj, wpt, 768);
    qkv_mfma<<<dim3(64, 18), 256, 0, stream>>>(xb, wqt,
                                               (__hip_bfloat16*)q, (__hip_bfloat16*)k, (__hip_bfloat16*)v);
    stats_mfma<<<dim3(BATCH * HEADS * 16), 256, 0, stream>>>(q, k, orow, hist);
    find_thr<<<dim3(BATCH), 256, 0, stream>>>(hist, thr);
    pv_mfma<<<dim3(BATCH * HEADS * 16), 256, 0, stream>>>(q, k, v, orow, thr,
                                                          (__hip_bfloat16*)aoutb);
    proj_mfma<<<dim3(64, 6), 256, 0, stream>>>(aoutb, wpt, b_proj, origin, out);
}